// Round 1
// baseline (858.065 us; speedup 1.0000x reference)
//
#include <hip/hip_runtime.h>
#include <hip/hip_bf16.h>

#define NN 2048
#define BB 8
#define NC 64

typedef __bf16 bf16_8 __attribute__((ext_vector_type(8)));
typedef float f32x4 __attribute__((ext_vector_type(4)));

__device__ __forceinline__ void gll16(const void* g, void* l) {
  __builtin_amdgcn_global_load_lds((const __attribute__((address_space(1))) void*)g,
                                   (__attribute__((address_space(3))) void*)l,
                                   16, 0, 0);
}

// fp32 -> bf16 convert + transpose: writes Ab (row-major bf16) and At (transpose, bf16)
__global__ __launch_bounds__(256)
void k_convert(const float* __restrict__ A, __bf16* __restrict__ Ab, __bf16* __restrict__ At) {
  __shared__ __bf16 tile[64][65];
  int b = blockIdx.z;
  const float* Asrc = A + (size_t)b * NN * NN;
  __bf16* Abd = Ab + (size_t)b * NN * NN;
  __bf16* Atd = At + (size_t)b * NN * NN;
  int tx = threadIdx.x & 63;
  int ty = threadIdx.x >> 6;
  int r0 = blockIdx.y * 64, c0 = blockIdx.x * 64;
#pragma unroll
  for (int r = 0; r < 64; r += 4) {
    float v = Asrc[(size_t)(r0 + r + ty) * NN + c0 + tx];
    __bf16 hv = (__bf16)v;
    Abd[(size_t)(r0 + r + ty) * NN + c0 + tx] = hv;
    tile[r + ty][tx] = hv;
  }
  __syncthreads();
#pragma unroll
  for (int r = 0; r < 64; r += 4) {
    Atd[(size_t)(c0 + r + ty) * NN + r0 + tx] = tile[tx][r + ty];
  }
}

// bf16 transpose
__global__ __launch_bounds__(256)
void k_transpose(const __bf16* __restrict__ X, __bf16* __restrict__ Xt) {
  __shared__ __bf16 tile[64][65];
  int b = blockIdx.z;
  const __bf16* Xb = X + (size_t)b * NN * NN;
  __bf16* Xtb = Xt + (size_t)b * NN * NN;
  int tx = threadIdx.x & 63;
  int ty = threadIdx.x >> 6;
  int r0 = blockIdx.y * 64, c0 = blockIdx.x * 64;
#pragma unroll
  for (int r = 0; r < 64; r += 4) {
    tile[r + ty][tx] = Xb[(size_t)(r0 + r + ty) * NN + c0 + tx];
  }
  __syncthreads();
#pragma unroll
  for (int r = 0; r < 64; r += 4) {
    Xtb[(size_t)(c0 + r + ty) * NN + r0 + tx] = tile[tx][r + ty];
  }
}

// C[m,n] = sum_k P[m,k] * Q[n,k]  (Q holds B^T row-major), bf16 in/out, fp32 acc.
// 128x128 tile per 256-thread block, BK=32, 16x16x32 bf16 MFMA, 4x4 frags/wave.
__global__ __launch_bounds__(256)
void k_gemm_bt(const __bf16* __restrict__ P, const __bf16* __restrict__ Q, __bf16* __restrict__ C) {
  __shared__ __align__(16) __bf16 As[128][32];
  __shared__ __align__(16) __bf16 Bs[128][32];
  int b = blockIdx.z;
  const __bf16* Pb = P + (size_t)b * NN * NN;
  const __bf16* Qb = Q + (size_t)b * NN * NN;
  __bf16* Cb = C + (size_t)b * NN * NN;
  int tid = threadIdx.x;
  int wave = tid >> 6;
  int lane = tid & 63;
  int tm = blockIdx.y * 128;
  int tn = blockIdx.x * 128;
  int wm = (wave >> 1) * 64;
  int wn = (wave & 1) * 64;

  // staging: per global_load_lds, one wave deposits 16 rows x 64B (lane -> base + lane*16B)
  int srow = lane >> 2;        // 0..15 row within 16-row group
  int scol = (lane & 3) * 8;   // bf16 element offset: 0,8,16,24
  int arow0 = wave * 32;       // this wave stages rows [arow0, arow0+32)

  int fr = lane & 15;          // fragment row (m or n within 16)
  int qk = (lane >> 4) * 8;    // fragment k offset (quad*8)

  f32x4 acc[4][4] = {};

  const __bf16* pA0 = Pb + (size_t)(tm + arow0 + srow) * NN + scol;
  const __bf16* pA1 = pA0 + (size_t)16 * NN;
  const __bf16* pB0 = Qb + (size_t)(tn + arow0 + srow) * NN + scol;
  const __bf16* pB1 = pB0 + (size_t)16 * NN;

  for (int k0 = 0; k0 < NN; k0 += 32) {
    gll16(pA0 + k0, &As[arow0][0]);
    gll16(pA1 + k0, &As[arow0 + 16][0]);
    gll16(pB0 + k0, &Bs[arow0][0]);
    gll16(pB1 + k0, &Bs[arow0 + 16][0]);
    __syncthreads();
    bf16_8 af[4], bfr[4];
#pragma unroll
    for (int i = 0; i < 4; ++i) {
      af[i]  = *(const bf16_8*)&As[wm + i * 16 + fr][qk];
      bfr[i] = *(const bf16_8*)&Bs[wn + i * 16 + fr][qk];
    }
#pragma unroll
    for (int im = 0; im < 4; ++im)
#pragma unroll
      for (int in = 0; in < 4; ++in)
        acc[im][in] = __builtin_amdgcn_mfma_f32_16x16x32_bf16(af[im], bfr[in], acc[im][in], 0, 0, 0);
    __syncthreads();
  }

  // C/D layout: col = lane&15, row = (lane>>4)*4 + reg
  int cr = (lane >> 4) * 4;
  int cc = lane & 15;
#pragma unroll
  for (int im = 0; im < 4; ++im)
#pragma unroll
    for (int in = 0; in < 4; ++in)
#pragma unroll
      for (int r = 0; r < 4; ++r)
        Cb[(size_t)(tm + wm + im * 16 + cr + r) * NN + (tn + wn + in * 16 + cc)] =
            (__bf16)acc[im][in][r];
}

// One wave per row n: 7 row-dot-products + final channel combine.
__global__ __launch_bounds__(256)
void k_reduce(const float* __restrict__ A, const float* __restrict__ h,
              const __bf16* __restrict__ At, const __bf16* __restrict__ A2,
              const __bf16* __restrict__ A2t, const __bf16* __restrict__ A3t,
              const __bf16* __restrict__ A4, const __bf16* __restrict__ A4t,
              float* __restrict__ out) {
  int b = blockIdx.y;
  int wave = threadIdx.x >> 6, lane = threadIdx.x & 63;
  int n = blockIdx.x * 4 + wave;
  size_t mb = (size_t)b * NN * NN;
  size_t rb = mb + (size_t)n * NN;
  float d2 = 0, d3 = 0, d4 = 0, d5 = 0, d6 = 0, d7 = 0, d8 = 0;
  for (int c = 0; c < NN; c += 512) {
    int k = c + lane * 8;
    const float4* ap = (const float4*)(A + rb + k);
    float4 a0 = ap[0], a1 = ap[1];
    bf16_8 vat  = *(const bf16_8*)(At + rb + k);
    bf16_8 va2  = *(const bf16_8*)(A2 + rb + k);
    bf16_8 va2t = *(const bf16_8*)(A2t + rb + k);
    bf16_8 va3t = *(const bf16_8*)(A3t + rb + k);
    bf16_8 va4  = *(const bf16_8*)(A4 + rb + k);
    bf16_8 va4t = *(const bf16_8*)(A4t + rb + k);
    float fa[8] = {a0.x, a0.y, a0.z, a0.w, a1.x, a1.y, a1.z, a1.w};
#pragma unroll
    for (int j = 0; j < 8; ++j) {
      float fat = (float)vat[j], fa2 = (float)va2[j], fa2t = (float)va2t[j],
            fa3t = (float)va3t[j], fa4 = (float)va4[j], fa4t = (float)va4t[j];
      d2 += fa[j] * fat;
      d3 += fa[j] * fa2t;
      d4 += fa2 * fa2t;
      d5 += fa4 * fat;
      d6 += fa4 * fa2t;
      d7 += fa4 * fa3t;
      d8 += fa4 * fa4t;
    }
  }
#pragma unroll
  for (int off = 32; off > 0; off >>= 1) {
    d2 += __shfl_xor(d2, off);
    d3 += __shfl_xor(d3, off);
    d4 += __shfl_xor(d4, off);
    d5 += __shfl_xor(d5, off);
    d6 += __shfl_xor(d6, off);
    d7 += __shfl_xor(d7, off);
    d8 += __shfl_xor(d8, off);
  }
  float d1 = A[mb + (size_t)n * NN + n];
  // lane == channel (NC=64)
  float r = h[lane] + h[64 + lane] * d1 + h[128 + lane] * d2 + h[192 + lane] * d3 +
            h[256 + lane] * d4 + h[320 + lane] * d5 + h[384 + lane] * d6 +
            h[448 + lane] * d7 + h[512 + lane] * d8;
  out[((size_t)b * NN + n) * NC + lane] = r;
}

extern "C" void kernel_launch(void* const* d_in, const int* in_sizes, int n_in,
                              void* d_out, int out_size, void* d_ws, size_t ws_size,
                              hipStream_t stream) {
  const float* A = (const float*)d_in[0];
  const float* h = (const float*)d_in[1];
  float* out = (float*)d_out;

  size_t elems = (size_t)BB * NN * NN;  // 33,554,432 elements per bf16 buffer (64 MiB)
  __bf16* Ab  = (__bf16*)d_ws;
  __bf16* At  = Ab + elems;
  __bf16* A2  = At + elems;
  __bf16* A2t = A2 + elems;
  __bf16* A3t = A2t + elems;
  __bf16* A4  = A3t + elems;
  __bf16* A4t = Ab;  // alias: Ab is dead after gemm1 (total ws use: 6 x 64 MiB = 384 MiB)

  dim3 bl(256);
  // A -> bf16 + transpose
  k_convert<<<dim3(32, 32, BB), bl, 0, stream>>>(A, Ab, At);
  // A2 = A @ A
  k_gemm_bt<<<dim3(16, 16, BB), bl, 0, stream>>>(Ab, At, A2);
  k_transpose<<<dim3(32, 32, BB), bl, 0, stream>>>(A2, A2t);
  // A3t = At @ A2t = (A2 @ A)^T = (A^3)^T
  k_gemm_bt<<<dim3(16, 16, BB), bl, 0, stream>>>(At, A2, A3t);
  // A4 = A2 @ A2
  k_gemm_bt<<<dim3(16, 16, BB), bl, 0, stream>>>(A2, A2t, A4);
  k_transpose<<<dim3(32, 32, BB), bl, 0, stream>>>(A4, A4t);
  // diagonals + channel combine
  k_reduce<<<dim3(NN / 4, BB), bl, 0, stream>>>(A, h, At, A2, A2t, A3t, A4, A4t, out);
}

// Round 2
// 803.118 us; speedup vs baseline: 1.0684x; 1.0684x over previous
//
#include <hip/hip_runtime.h>
#include <hip/hip_bf16.h>

#define NN 2048
#define BB 8
#define NC 64

typedef __bf16 bf16_8 __attribute__((ext_vector_type(8)));
typedef float f32x16 __attribute__((ext_vector_type(16)));

__device__ __forceinline__ void gll16(const void* g, void* l) {
  __builtin_amdgcn_global_load_lds((const __attribute__((address_space(1))) void*)g,
                                   (__attribute__((address_space(3))) void*)l,
                                   16, 0, 0);
}

// fp32 -> bf16 convert + transpose: writes Ab (row-major bf16) and At (transpose, bf16)
__global__ __launch_bounds__(256)
void k_convert(const float* __restrict__ A, __bf16* __restrict__ Ab, __bf16* __restrict__ At) {
  __shared__ __bf16 tile[64][65];
  int b = blockIdx.z;
  const float* Asrc = A + (size_t)b * NN * NN;
  __bf16* Abd = Ab + (size_t)b * NN * NN;
  __bf16* Atd = At + (size_t)b * NN * NN;
  int tx = threadIdx.x & 63;
  int ty = threadIdx.x >> 6;
  int r0 = blockIdx.y * 64, c0 = blockIdx.x * 64;
#pragma unroll
  for (int r = 0; r < 64; r += 4) {
    float v = Asrc[(size_t)(r0 + r + ty) * NN + c0 + tx];
    __bf16 hv = (__bf16)v;
    Abd[(size_t)(r0 + r + ty) * NN + c0 + tx] = hv;
    tile[r + ty][tx] = hv;
  }
  __syncthreads();
#pragma unroll
  for (int r = 0; r < 64; r += 4) {
    Atd[(size_t)(c0 + r + ty) * NN + r0 + tx] = tile[tx][r + ty];
  }
}

// bf16 transpose
__global__ __launch_bounds__(256)
void k_transpose(const __bf16* __restrict__ X, __bf16* __restrict__ Xt) {
  __shared__ __bf16 tile[64][65];
  int b = blockIdx.z;
  const __bf16* Xb = X + (size_t)b * NN * NN;
  __bf16* Xtb = Xt + (size_t)b * NN * NN;
  int tx = threadIdx.x & 63;
  int ty = threadIdx.x >> 6;
  int r0 = blockIdx.y * 64, c0 = blockIdx.x * 64;
#pragma unroll
  for (int r = 0; r < 64; r += 4) {
    tile[r + ty][tx] = Xb[(size_t)(r0 + r + ty) * NN + c0 + tx];
  }
  __syncthreads();
#pragma unroll
  for (int r = 0; r < 64; r += 4) {
    Xtb[(size_t)(c0 + r + ty) * NN + r0 + tx] = tile[tx][r + ty];
  }
}

// C[m,n] = sum_k P[m,k] * Q[n,k]  (Q holds B^T row-major), bf16 in/out, fp32 acc.
// 128x128 tile / 256 threads, BK=64, 32x32x16 bf16 MFMA, 2x2 frags/wave (64x64).
// LDS chunk-XOR swizzle: row r's 16B-chunk c stored at position c ^ (r&7);
// staging permutes the SOURCE chunk (c = (lane&7) ^ (lane>>3)) so the
// global_load_lds lane->base+16*lane dest constraint is honored.
__global__ __launch_bounds__(256)
void k_gemm_bt(const __bf16* __restrict__ P, const __bf16* __restrict__ Q, __bf16* __restrict__ C) {
  __shared__ __align__(16) __bf16 As[128][64];
  __shared__ __align__(16) __bf16 Bs[128][64];
  int b = blockIdx.z;
  const __bf16* Pb = P + (size_t)b * NN * NN;
  const __bf16* Qb = Q + (size_t)b * NN * NN;
  __bf16* Cb = C + (size_t)b * NN * NN;
  int tid = threadIdx.x;
  int wave = tid >> 6;
  int lane = tid & 63;
  int tm = blockIdx.y * 128;
  int tn = blockIdx.x * 128;
  int wm = (wave >> 1) * 64;
  int wn = (wave & 1) * 64;

  // staging: each gll16 deposits 8 rows x 128B; this wave stages rows [arow0, arow0+32)
  int arow0 = wave * 32;
  int srow = lane >> 3;                 // 0..7 row within 8-row group
  int sc = (lane & 7) ^ srow;           // swizzled source chunk (16B units)
  const __bf16* pA = Pb + (size_t)(tm + arow0 + srow) * NN + sc * 8;
  const __bf16* pB = Qb + (size_t)(tn + arow0 + srow) * NN + sc * 8;

  int am = lane & 31;   // frag row within 32
  int ah = lane >> 5;   // k-half (0/1)

  f32x16 acc[2][2] = {};

  for (int k0 = 0; k0 < NN; k0 += 64) {
#pragma unroll
    for (int g = 0; g < 4; ++g) {
      gll16(pA + (size_t)(g * 8) * NN + k0, &As[arow0 + g * 8][0]);
      gll16(pB + (size_t)(g * 8) * NN + k0, &Bs[arow0 + g * 8][0]);
    }
    __syncthreads();
#pragma unroll
    for (int ks = 0; ks < 4; ++ks) {
      int cch = ks * 2 + ah;  // chunk index of this frag's k-slice
      bf16_8 af[2], bf2[2];
#pragma unroll
      for (int i = 0; i < 2; ++i) {
        int ra = wm + i * 32 + am;
        int rb2 = wn + i * 32 + am;
        af[i]  = *(const bf16_8*)&As[ra][(cch ^ (ra & 7)) * 8];
        bf2[i] = *(const bf16_8*)&Bs[rb2][(cch ^ (rb2 & 7)) * 8];
      }
#pragma unroll
      for (int im = 0; im < 2; ++im)
#pragma unroll
        for (int in = 0; in < 2; ++in)
          acc[im][in] = __builtin_amdgcn_mfma_f32_32x32x16_bf16(af[im], bf2[in], acc[im][in], 0, 0, 0);
    }
    __syncthreads();
  }

  // C/D layout (32x32): col = lane&31, row = (reg&3) + 8*(reg>>2) + 4*(lane>>5)
  int cc = lane & 31;
  int rq = (lane >> 5) * 4;
#pragma unroll
  for (int im = 0; im < 2; ++im)
#pragma unroll
    for (int in = 0; in < 2; ++in)
#pragma unroll
      for (int reg = 0; reg < 16; ++reg) {
        int row = (reg & 3) + 8 * (reg >> 2) + rq;
        Cb[(size_t)(tm + wm + im * 32 + row) * NN + (tn + wn + in * 32 + cc)] =
            (__bf16)acc[im][in][reg];
      }
}

// One wave per row n: 7 row-dot-products + final channel combine.
__global__ __launch_bounds__(256)
void k_reduce(const float* __restrict__ A, const float* __restrict__ h,
              const __bf16* __restrict__ At, const __bf16* __restrict__ A2,
              const __bf16* __restrict__ A2t, const __bf16* __restrict__ A3t,
              const __bf16* __restrict__ A4, const __bf16* __restrict__ A4t,
              float* __restrict__ out) {
  int b = blockIdx.y;
  int wave = threadIdx.x >> 6, lane = threadIdx.x & 63;
  int n = blockIdx.x * 4 + wave;
  size_t mb = (size_t)b * NN * NN;
  size_t rb = mb + (size_t)n * NN;
  float d2 = 0, d3 = 0, d4 = 0, d5 = 0, d6 = 0, d7 = 0, d8 = 0;
  for (int c = 0; c < NN; c += 512) {
    int k = c + lane * 8;
    const float4* ap = (const float4*)(A + rb + k);
    float4 a0 = ap[0], a1 = ap[1];
    bf16_8 vat  = *(const bf16_8*)(At + rb + k);
    bf16_8 va2  = *(const bf16_8*)(A2 + rb + k);
    bf16_8 va2t = *(const bf16_8*)(A2t + rb + k);
    bf16_8 va3t = *(const bf16_8*)(A3t + rb + k);
    bf16_8 va4  = *(const bf16_8*)(A4 + rb + k);
    bf16_8 va4t = *(const bf16_8*)(A4t + rb + k);
    float fa[8] = {a0.x, a0.y, a0.z, a0.w, a1.x, a1.y, a1.z, a1.w};
#pragma unroll
    for (int j = 0; j < 8; ++j) {
      float fat = (float)vat[j], fa2 = (float)va2[j], fa2t = (float)va2t[j],
            fa3t = (float)va3t[j], fa4 = (float)va4[j], fa4t = (float)va4t[j];
      d2 += fa[j] * fat;
      d3 += fa[j] * fa2t;
      d4 += fa2 * fa2t;
      d5 += fa4 * fat;
      d6 += fa4 * fa2t;
      d7 += fa4 * fa3t;
      d8 += fa4 * fa4t;
    }
  }
#pragma unroll
  for (int off = 32; off > 0; off >>= 1) {
    d2 += __shfl_xor(d2, off);
    d3 += __shfl_xor(d3, off);
    d4 += __shfl_xor(d4, off);
    d5 += __shfl_xor(d5, off);
    d6 += __shfl_xor(d6, off);
    d7 += __shfl_xor(d7, off);
    d8 += __shfl_xor(d8, off);
  }
  float d1 = A[mb + (size_t)n * NN + n];
  // lane == channel (NC=64)
  float r = h[lane] + h[64 + lane] * d1 + h[128 + lane] * d2 + h[192 + lane] * d3 +
            h[256 + lane] * d4 + h[320 + lane] * d5 + h[384 + lane] * d6 +
            h[448 + lane] * d7 + h[512 + lane] * d8;
  out[((size_t)b * NN + n) * NC + lane] = r;
}

extern "C" void kernel_launch(void* const* d_in, const int* in_sizes, int n_in,
                              void* d_out, int out_size, void* d_ws, size_t ws_size,
                              hipStream_t stream) {
  const float* A = (const float*)d_in[0];
  const float* h = (const float*)d_in[1];
  float* out = (float*)d_out;

  size_t elems = (size_t)BB * NN * NN;  // 33,554,432 elements per bf16 buffer (64 MiB)
  __bf16* Ab  = (__bf16*)d_ws;
  __bf16* At  = Ab + elems;
  __bf16* A2  = At + elems;
  __bf16* A2t = A2 + elems;
  __bf16* A3t = A2t + elems;
  __bf16* A4  = A3t + elems;
  __bf16* A4t = Ab;  // alias: Ab is dead after gemm1 (total ws use: 6 x 64 MiB = 384 MiB)

  dim3 bl(256);
  // A -> bf16 + transpose
  k_convert<<<dim3(32, 32, BB), bl, 0, stream>>>(A, Ab, At);
  // A2 = A @ A
  k_gemm_bt<<<dim3(16, 16, BB), bl, 0, stream>>>(Ab, At, A2);
  k_transpose<<<dim3(32, 32, BB), bl, 0, stream>>>(A2, A2t);
  // A3t = At @ A2t = (A2 @ A)^T = (A^3)^T
  k_gemm_bt<<<dim3(16, 16, BB), bl, 0, stream>>>(At, A2, A3t);
  // A4 = A2 @ A2
  k_gemm_bt<<<dim3(16, 16, BB), bl, 0, stream>>>(A2, A2t, A4);
  k_transpose<<<dim3(32, 32, BB), bl, 0, stream>>>(A4, A4t);
  // diagonals + channel combine
  k_reduce<<<dim3(NN / 4, BB), bl, 0, stream>>>(A, h, At, A2, A2t, A3t, A4, A4t, out);
}

// Round 3
// 780.749 us; speedup vs baseline: 1.0990x; 1.0287x over previous
//
#include <hip/hip_runtime.h>
#include <hip/hip_bf16.h>

#define NN 2048
#define BB 8
#define NC 64

typedef __bf16 bf16_8 __attribute__((ext_vector_type(8)));
typedef __bf16 bf16_4 __attribute__((ext_vector_type(4)));
typedef float f32x16 __attribute__((ext_vector_type(16)));

__device__ __forceinline__ void gll16(const void* g, void* l) {
  __builtin_amdgcn_global_load_lds((const __attribute__((address_space(1))) void*)g,
                                   (__attribute__((address_space(3))) void*)l,
                                   16, 0, 0);
}

// fp32 -> bf16 convert + transpose, 16B/lane global reads, 8B/16B writes.
__global__ __launch_bounds__(256)
void k_convert(const float* __restrict__ A, __bf16* __restrict__ Ab, __bf16* __restrict__ At) {
  __shared__ __bf16 tile[64][65];
  int b = blockIdx.z;
  const float* Asrc = A + (size_t)b * NN * NN;
  __bf16* Abd = Ab + (size_t)b * NN * NN;
  __bf16* Atd = At + (size_t)b * NN * NN;
  int r0 = blockIdx.y * 64, c0 = blockIdx.x * 64;
  int row = threadIdx.x >> 4;          // 0..15
  int col4 = (threadIdx.x & 15) * 4;   // 0..60
#pragma unroll
  for (int rr = 0; rr < 64; rr += 16) {
    float4 v = *(const float4*)&Asrc[(size_t)(r0 + row + rr) * NN + c0 + col4];
    bf16_4 hv;
    hv[0] = (__bf16)v.x; hv[1] = (__bf16)v.y; hv[2] = (__bf16)v.z; hv[3] = (__bf16)v.w;
    *(bf16_4*)&Abd[(size_t)(r0 + row + rr) * NN + c0 + col4] = hv;
    tile[row + rr][col4 + 0] = hv[0];
    tile[row + rr][col4 + 1] = hv[1];
    tile[row + rr][col4 + 2] = hv[2];
    tile[row + rr][col4 + 3] = hv[3];
  }
  __syncthreads();
  int row2 = threadIdx.x >> 3;         // 0..31
  int col8 = (threadIdx.x & 7) * 8;    // 0..56
#pragma unroll
  for (int rr = 0; rr < 64; rr += 32) {
    bf16_8 v;
#pragma unroll
    for (int j = 0; j < 8; ++j) v[j] = tile[col8 + j][row2 + rr];
    *(bf16_8*)&Atd[(size_t)(c0 + row2 + rr) * NN + r0 + col8] = v;
  }
}

// bf16 transpose, 16B/lane global reads and writes.
__global__ __launch_bounds__(256)
void k_transpose(const __bf16* __restrict__ X, __bf16* __restrict__ Xt) {
  __shared__ __bf16 tile[64][65];
  int b = blockIdx.z;
  const __bf16* Xb = X + (size_t)b * NN * NN;
  __bf16* Xtb = Xt + (size_t)b * NN * NN;
  int r0 = blockIdx.y * 64, c0 = blockIdx.x * 64;
  int row = threadIdx.x >> 3;          // 0..31
  int col8 = (threadIdx.x & 7) * 8;    // 0..56
#pragma unroll
  for (int rr = 0; rr < 64; rr += 32) {
    bf16_8 v = *(const bf16_8*)&Xb[(size_t)(r0 + row + rr) * NN + c0 + col8];
#pragma unroll
    for (int j = 0; j < 8; ++j) tile[row + rr][col8 + j] = v[j];
  }
  __syncthreads();
#pragma unroll
  for (int rr = 0; rr < 64; rr += 32) {
    bf16_8 v;
#pragma unroll
    for (int j = 0; j < 8; ++j) v[j] = tile[col8 + j][row + rr];
    *(bf16_8*)&Xtb[(size_t)(c0 + row + rr) * NN + r0 + col8] = v;
  }
}

// C[m,n] = sum_k P[m,k] * Q[n,k], bf16 in/out, fp32 acc.
// Block tile 256(M)x128(N), BK=64, 32x32x16 MFMA, 4 waves each 128x64 (4x2 frags).
// LDS chunk-XOR swizzle (conflict-free for both gll16 deposits and frag reads).
__global__ __launch_bounds__(256, 2)
void k_gemm_bt(const __bf16* __restrict__ P, const __bf16* __restrict__ Q, __bf16* __restrict__ C) {
  __shared__ __align__(16) __bf16 As[256][64];  // 32 KB
  __shared__ __align__(16) __bf16 Bs[128][64];  // 16 KB
  int b = blockIdx.z;
  const __bf16* Pb = P + (size_t)b * NN * NN;
  const __bf16* Qb = Q + (size_t)b * NN * NN;
  __bf16* Cb = C + (size_t)b * NN * NN;
  int tid = threadIdx.x;
  int wave = tid >> 6;
  int lane = tid & 63;
  int tm = blockIdx.y * 256;
  int tn = blockIdx.x * 128;
  int wm = (wave >> 1) * 128;   // wave M-offset (2 wave-rows)
  int wn = (wave & 1) * 64;     // wave N-offset (2 wave-cols)

  // staging: per gll16 a wave deposits 8 rows x 128B; src chunk swizzled so
  // row r's 16B-chunk c lands at LDS position c ^ (r&7).
  int srow = lane >> 3;              // 0..7
  int sc = (lane & 7) ^ srow;        // swizzled source chunk
  int arowA = wave * 64;             // this wave stages As rows [arowA, arowA+64)
  int arowB = wave * 32;             // and Bs rows [arowB, arowB+32)
  const __bf16* pA = Pb + (size_t)(tm + arowA + srow) * NN + sc * 8;
  const __bf16* pB = Qb + (size_t)(tn + arowB + srow) * NN + sc * 8;

  int am = lane & 31;   // frag row within 32
  int ah = lane >> 5;   // k-half (0/1)

  f32x16 acc[4][2] = {};

  for (int k0 = 0; k0 < NN; k0 += 64) {
#pragma unroll
    for (int g = 0; g < 8; ++g)
      gll16(pA + (size_t)(g * 8) * NN + k0, &As[arowA + g * 8][0]);
#pragma unroll
    for (int g = 0; g < 4; ++g)
      gll16(pB + (size_t)(g * 8) * NN + k0, &Bs[arowB + g * 8][0]);
    __syncthreads();
#pragma unroll
    for (int ks = 0; ks < 4; ++ks) {
      int cch = ks * 2 + ah;  // 16B-chunk index of this frag's k-slice
      bf16_8 af[4], bf2[2];
#pragma unroll
      for (int i = 0; i < 4; ++i) {
        int ra = wm + i * 32 + am;
        af[i] = *(const bf16_8*)&As[ra][(cch ^ (ra & 7)) * 8];
      }
#pragma unroll
      for (int i = 0; i < 2; ++i) {
        int rb2 = wn + i * 32 + am;
        bf2[i] = *(const bf16_8*)&Bs[rb2][(cch ^ (rb2 & 7)) * 8];
      }
#pragma unroll
      for (int im = 0; im < 4; ++im)
#pragma unroll
        for (int in = 0; in < 2; ++in)
          acc[im][in] = __builtin_amdgcn_mfma_f32_32x32x16_bf16(af[im], bf2[in], acc[im][in], 0, 0, 0);
    }
    __syncthreads();
  }

  // C/D layout (32x32): col = lane&31, row = (reg&3) + 8*(reg>>2) + 4*(lane>>5)
  int cc = lane & 31;
  int rq = (lane >> 5) * 4;
#pragma unroll
  for (int im = 0; im < 4; ++im)
#pragma unroll
    for (int in = 0; in < 2; ++in)
#pragma unroll
      for (int reg = 0; reg < 16; ++reg) {
        int row = (reg & 3) + 8 * (reg >> 2) + rq;
        Cb[(size_t)(tm + wm + im * 32 + row) * NN + (tn + wn + in * 32 + cc)] =
            (__bf16)acc[im][in][reg];
      }
}

// One wave per row n: 7 row-dot-products + final channel combine.
__global__ __launch_bounds__(256)
void k_reduce(const float* __restrict__ A, const float* __restrict__ h,
              const __bf16* __restrict__ At, const __bf16* __restrict__ A2,
              const __bf16* __restrict__ A2t, const __bf16* __restrict__ A3t,
              const __bf16* __restrict__ A4, const __bf16* __restrict__ A4t,
              float* __restrict__ out) {
  int b = blockIdx.y;
  int wave = threadIdx.x >> 6, lane = threadIdx.x & 63;
  int n = blockIdx.x * 4 + wave;
  size_t mb = (size_t)b * NN * NN;
  size_t rb = mb + (size_t)n * NN;
  float d2 = 0, d3 = 0, d4 = 0, d5 = 0, d6 = 0, d7 = 0, d8 = 0;
  for (int c = 0; c < NN; c += 512) {
    int k = c + lane * 8;
    const float4* ap = (const float4*)(A + rb + k);
    float4 a0 = ap[0], a1 = ap[1];
    bf16_8 vat  = *(const bf16_8*)(At + rb + k);
    bf16_8 va2  = *(const bf16_8*)(A2 + rb + k);
    bf16_8 va2t = *(const bf16_8*)(A2t + rb + k);
    bf16_8 va3t = *(const bf16_8*)(A3t + rb + k);
    bf16_8 va4  = *(const bf16_8*)(A4 + rb + k);
    bf16_8 va4t = *(const bf16_8*)(A4t + rb + k);
    float fa[8] = {a0.x, a0.y, a0.z, a0.w, a1.x, a1.y, a1.z, a1.w};
#pragma unroll
    for (int j = 0; j < 8; ++j) {
      float fat = (float)vat[j], fa2 = (float)va2[j], fa2t = (float)va2t[j],
            fa3t = (float)va3t[j], fa4 = (float)va4[j], fa4t = (float)va4t[j];
      d2 += fa[j] * fat;
      d3 += fa[j] * fa2t;
      d4 += fa2 * fa2t;
      d5 += fa4 * fat;
      d6 += fa4 * fa2t;
      d7 += fa4 * fa3t;
      d8 += fa4 * fa4t;
    }
  }
#pragma unroll
  for (int off = 32; off > 0; off >>= 1) {
    d2 += __shfl_xor(d2, off);
    d3 += __shfl_xor(d3, off);
    d4 += __shfl_xor(d4, off);
    d5 += __shfl_xor(d5, off);
    d6 += __shfl_xor(d6, off);
    d7 += __shfl_xor(d7, off);
    d8 += __shfl_xor(d8, off);
  }
  float d1 = A[mb + (size_t)n * NN + n];
  // lane == channel (NC=64)
  float r = h[lane] + h[64 + lane] * d1 + h[128 + lane] * d2 + h[192 + lane] * d3 +
            h[256 + lane] * d4 + h[320 + lane] * d5 + h[384 + lane] * d6 +
            h[448 + lane] * d7 + h[512 + lane] * d8;
  out[((size_t)b * NN + n) * NC + lane] = r;
}

extern "C" void kernel_launch(void* const* d_in, const int* in_sizes, int n_in,
                              void* d_out, int out_size, void* d_ws, size_t ws_size,
                              hipStream_t stream) {
  const float* A = (const float*)d_in[0];
  const float* h = (const float*)d_in[1];
  float* out = (float*)d_out;

  size_t elems = (size_t)BB * NN * NN;  // 33,554,432 elements per bf16 buffer (64 MiB)
  __bf16* Ab  = (__bf16*)d_ws;
  __bf16* At  = Ab + elems;
  __bf16* A2  = At + elems;
  __bf16* A2t = A2 + elems;
  __bf16* A3t = A2t + elems;
  __bf16* A4  = A3t + elems;
  __bf16* A4t = Ab;  // alias: Ab is dead after gemm1 (total ws use: 6 x 64 MiB = 384 MiB)

  dim3 bl(256);
  // A -> bf16 + transpose
  k_convert<<<dim3(32, 32, BB), bl, 0, stream>>>(A, Ab, At);
  // A2 = A @ A
  k_gemm_bt<<<dim3(16, 8, BB), bl, 0, stream>>>(Ab, At, A2);
  k_transpose<<<dim3(32, 32, BB), bl, 0, stream>>>(A2, A2t);
  // A3t = At @ A2t = (A2 @ A)^T = (A^3)^T
  k_gemm_bt<<<dim3(16, 8, BB), bl, 0, stream>>>(At, A2, A3t);
  // A4 = A2 @ A2
  k_gemm_bt<<<dim3(16, 8, BB), bl, 0, stream>>>(A2, A2t, A4);
  k_transpose<<<dim3(32, 32, BB), bl, 0, stream>>>(A4, A4t);
  // diagonals + channel combine
  k_reduce<<<dim3(NN / 4, BB), bl, 0, stream>>>(A, h, At, A2, A2t, A3t, A4, A4t, out);
}